// Round 1
// baseline (107.777 us; speedup 1.0000x reference)
//
#include <hip/hip_runtime.h>
#include <float.h>

#define POOL 7
#define FW 2048
#define FH 2048

__global__ __launch_bounds__(128) void roi_pool_fc_kernel(
    const float* __restrict__ feature,   // [2, 2048, 2048]
    const float* __restrict__ boxes,     // [N, 6]
    const int*   __restrict__ coords,    // [N, 4] (y1, x1, y2, x2)
    const float* __restrict__ fc_w,      // [4, 98]
    const float* __restrict__ fc_b,      // [4]
    float* __restrict__ out,             // [N, 6]
    int N)
{
    const int n = blockIdx.x;
    const int t = threadIdx.x;

    __shared__ float pooled[98];   // channel-major flatten: c*49 + i*7 + j
    __shared__ float delta[4];

    const int y1 = coords[n * 4 + 0];
    const int x1 = coords[n * 4 + 1];
    const int y2 = coords[n * 4 + 2];
    const int x2 = coords[n * 4 + 3];
    const int h = y2 - y1;   // 7 <= h <= 96
    const int w = x2 - x1;   // 7 <= w <= 96

    if (t < 98) {
        const int c   = t / 49;
        const int rem = t - c * 49;
        const int i   = rem / 7;
        const int j   = rem - i * 7;

        // PyTorch adaptive pooling bins: [floor(i*h/P), ceil((i+1)*h/P))
        const int sr = (i * h) / POOL;
        const int er = ((i + 1) * h + POOL - 1) / POOL;
        const int sc = (j * w) / POOL;
        const int ec = ((j + 1) * w + POOL - 1) / POOL;

        const float* base = feature + (size_t)c * FH * FW;
        float m = -FLT_MAX;
        for (int r = sr; r < er; ++r) {
            const float* rowp = base + (size_t)(y1 + r) * FW + x1;
            for (int cc = sc; cc < ec; ++cc) {
                m = fmaxf(m, rowp[cc]);
            }
        }
        pooled[t] = m;
    }
    __syncthreads();

    if (t < 4) {
        float acc = fc_b[t];
        const float* wrow = fc_w + t * 98;
        #pragma unroll 7
        for (int k = 0; k < 98; ++k) {
            acc = fmaf(pooled[k], wrow[k], acc);
        }
        delta[t] = fmaxf(acc, 0.0f);   // ReLU
    }
    __syncthreads();

    if (t < 6) {
        float v = boxes[n * 6 + t];
        if (t >= 2) v += delta[t - 2];
        out[n * 6 + t] = v;
    }
}

extern "C" void kernel_launch(void* const* d_in, const int* in_sizes, int n_in,
                              void* d_out, int out_size, void* d_ws, size_t ws_size,
                              hipStream_t stream) {
    const float* feature = (const float*)d_in[0];  // [1,2,2048,2048] fp32
    const float* boxes   = (const float*)d_in[1];  // [N,6] fp32
    const int*   coords  = (const int*)d_in[2];    // [N,4] int32
    const float* fc_w    = (const float*)d_in[3];  // [4,98] fp32
    const float* fc_b    = (const float*)d_in[4];  // [4] fp32
    float* out = (float*)d_out;                    // [N,6] fp32

    const int N = in_sizes[2] / 4;
    roi_pool_fc_kernel<<<N, 128, 0, stream>>>(feature, boxes, coords, fc_w, fc_b, out, N);
}

// Round 2
// 107.658 us; speedup vs baseline: 1.0011x; 1.0011x over previous
//
#include <hip/hip_runtime.h>
#include <float.h>

#define POOL 7
#define FW 2048
#define FH 2048
#define CROP 96
#define LSTRIDE 97   // +1 pad to break 32-bank alignment on row stride

// One block per box. Phase 1: stage full 96x96 channel window into LDS
// (always in-bounds: x1 <= 2048-96-1, y1 likewise per setup_inputs).
// Phase 2: 4 threads per pooled output, row-split, shfl_xor combine.
// Phase 3: tiny 98->4 FC + ReLU, add into boxes row.
__global__ __launch_bounds__(256, 4) void roi_pool_fc_kernel(
    const float* __restrict__ feature,   // [2, 2048, 2048]
    const float* __restrict__ boxes,     // [N, 6]
    const int*   __restrict__ coords,    // [N, 4] (y1, x1, y2, x2)
    const float* __restrict__ fc_w,      // [4, 98]
    const float* __restrict__ fc_b,      // [4]
    float* __restrict__ out,             // [N, 6]
    int N)
{
    const int n = blockIdx.x;
    const int t = threadIdx.x;

    __shared__ float lds[CROP * LSTRIDE];   // 37,248 B -> 4 blocks/CU
    __shared__ float pooled[98];            // channel-major: c*49 + i*7 + j
    __shared__ float delta[4];

    const int y1 = coords[n * 4 + 0];
    const int x1 = coords[n * 4 + 1];
    const int h  = coords[n * 4 + 2] - y1;   // 7 <= h <= 96
    const int w  = coords[n * 4 + 3] - x1;   // 7 <= w <= 96

    // Compute-phase mapping: t -> (output o, row-split slot s)
    const int o = t >> 2;          // 0..48 for t < 196
    const int s = t & 3;
    const int i = o / 7;
    const int j = o % 7;
    int sr = 0, er = 0, sc = 0, ec = 0;
    if (t < 196) {
        // PyTorch adaptive bins: [floor(i*h/P), ceil((i+1)*h/P))
        sr = (i * h) / POOL;
        er = ((i + 1) * h + POOL - 1) / POOL;
        sc = (j * w) / POOL;
        ec = ((j + 1) * w + POOL - 1) / POOL;
    }

    for (int c = 0; c < 2; ++c) {
        // ---- Phase 1: coalesced, fully-unrolled staging (9216 elems / 256 thr = 36)
        const float* base = feature + ((size_t)c * FH + y1) * FW + x1;
        #pragma unroll
        for (int k = 0; k < (CROP * CROP) / 256; ++k) {
            const int idx = t + k * 256;
            const int r   = idx / CROP;          // const-div -> magic mul
            const int cc  = idx - r * CROP;
            lds[r * LSTRIDE + cc] = base[(size_t)r * FW + cc];
        }
        __syncthreads();

        // ---- Phase 2: bin max from LDS, 4-way row split per output
        if (t < 196) {
            float m = -FLT_MAX;
            for (int r = sr + s; r < er; r += 4) {
                const float* rowp = lds + r * LSTRIDE;
                for (int cc = sc; cc < ec; ++cc)
                    m = fmaxf(m, rowp[cc]);
            }
            // combine the 4 row-split partials (lanes o*4..o*4+3, same wave)
            m = fmaxf(m, __shfl_xor(m, 1, 64));
            m = fmaxf(m, __shfl_xor(m, 2, 64));
            if (s == 0) pooled[c * 49 + o] = m;
        }
        __syncthreads();   // lds reuse for next channel; pooled visible after loop
    }

    // ---- Phase 3: FC (98 -> 4) + ReLU
    if (t < 4) {
        float acc = fc_b[t];
        const float* wrow = fc_w + t * 98;
        #pragma unroll
        for (int k = 0; k < 98; ++k)
            acc = fmaf(pooled[k], wrow[k], acc);
        delta[t] = fmaxf(acc, 0.0f);
    }
    __syncthreads();

    if (t < 6) {
        float v = boxes[n * 6 + t];
        if (t >= 2) v += delta[t - 2];
        out[n * 6 + t] = v;
    }
}

extern "C" void kernel_launch(void* const* d_in, const int* in_sizes, int n_in,
                              void* d_out, int out_size, void* d_ws, size_t ws_size,
                              hipStream_t stream) {
    const float* feature = (const float*)d_in[0];  // [1,2,2048,2048] fp32
    const float* boxes   = (const float*)d_in[1];  // [N,6] fp32
    const int*   coords  = (const int*)d_in[2];    // [N,4] int32
    const float* fc_w    = (const float*)d_in[3];  // [4,98] fp32
    const float* fc_b    = (const float*)d_in[4];  // [4] fp32
    float* out = (float*)d_out;                    // [N,6] fp32

    const int N = in_sizes[2] / 4;
    roi_pool_fc_kernel<<<N, 256, 0, stream>>>(feature, boxes, coords, fc_w, fc_b, out, N);
}

// Round 3
// 89.536 us; speedup vs baseline: 1.2037x; 1.2024x over previous
//
#include <hip/hip_runtime.h>
#include <float.h>

#define POOL 7
#define FW 2048
#define FH 2048
#define CROP 96
#define LROW 100   // floats per LDS row: aligned window of 25 float4

// One block per box.
//  Phase 0: prefetch ch0 window (h rows x 100 aligned cols) as float4 -> regs -> LDS
//  Phase 1: bin-max ch0 from LDS (4 threads/output, shfl combine); ch1 loads in flight
//  Phase 2: bin-max ch1; then 98->4 FC (32 lanes/output + shfl reduce) + ReLU + add.
__global__ __launch_bounds__(256, 4) void roi_pool_fc_kernel(
    const float* __restrict__ feature,   // [2, 2048, 2048]
    const float* __restrict__ boxes,     // [N, 6]
    const int*   __restrict__ coords,    // [N, 4] (y1, x1, y2, x2)
    const float* __restrict__ fc_w,      // [4, 98]
    const float* __restrict__ fc_b,      // [4]
    float* __restrict__ out,             // [N, 6]
    int N)
{
    const int n = blockIdx.x;
    const int t = threadIdx.x;

    __shared__ float lds[CROP * LROW];   // 38,400 B -> 4 blocks/CU
    __shared__ float pooled[98];         // channel-major: c*49 + i*7 + j
    __shared__ float delta[4];

    const int y1 = coords[n * 4 + 0];
    const int x1 = coords[n * 4 + 1];
    const int h  = coords[n * 4 + 2] - y1;   // 7 <= h <= 96
    const int w  = coords[n * 4 + 3] - x1;   // 7 <= w <= 96

    const int x1a = x1 & ~3;        // 16B-aligned window start; x1a+100 <= 2048 always
    const int off = x1 - x1a;       // 0..3

    // Compute-phase mapping: t -> (output o, row-split slot s)
    const int o = t >> 2;           // 0..48 for t < 196
    const int s = t & 3;
    const int i = o / 7;
    const int j = o % 7;
    int sr = 0, er = 0, sc = 0, ec = 0;
    if (t < 196) {
        sr = (i * h) / POOL;
        er = ((i + 1) * h + POOL - 1) / POOL;
        sc = (j * w) / POOL + off;
        ec = ((j + 1) * w + POOL - 1) / POOL + off;
    }

    // Staging geometry: 96 rows x 25 float4 = 2400 vecs; 10 chunks of 256.
    const float* b0 = feature + (size_t)y1 * FW + x1a;              // ch0
    const float* b1 = feature + ((size_t)FH + y1) * FW + x1a;       // ch1

    float4 regs[10];
    int vrow[10], vc4[10];
    bool vok[10];
    #pragma unroll
    for (int k = 0; k < 10; ++k) {
        const int v = t + k * 256;
        const int r = v / 25;
        vrow[k] = r;
        vc4[k]  = v - r * 25;
        vok[k]  = (v < 2400) && (r < h);
        regs[k] = vok[k] ? ((const float4*)(b0 + (size_t)r * FW))[vc4[k]]
                         : make_float4(0.f, 0.f, 0.f, 0.f);
    }
    #pragma unroll
    for (int k = 0; k < 10; ++k)
        if (vok[k]) ((float4*)&lds[vrow[k] * LROW])[vc4[k]] = regs[k];
    __syncthreads();

    // Prefetch ch1 while ch0 bin-max runs (loads land in regs, no LDS touch)
    #pragma unroll
    for (int k = 0; k < 10; ++k)
        regs[k] = vok[k] ? ((const float4*)(b1 + (size_t)vrow[k] * FW))[vc4[k]]
                         : make_float4(0.f, 0.f, 0.f, 0.f);

    // Phase 1: bin max ch0
    if (t < 196) {
        float m = -FLT_MAX;
        for (int r = sr + s; r < er; r += 4) {
            const float* rowp = lds + r * LROW;
            for (int cc = sc; cc < ec; ++cc)
                m = fmaxf(m, rowp[cc]);
        }
        m = fmaxf(m, __shfl_xor(m, 1, 64));
        m = fmaxf(m, __shfl_xor(m, 2, 64));
        if (s == 0) pooled[o] = m;
    }
    __syncthreads();   // all ch0 LDS reads done before overwrite

    #pragma unroll
    for (int k = 0; k < 10; ++k)
        if (vok[k]) ((float4*)&lds[vrow[k] * LROW])[vc4[k]] = regs[k];
    __syncthreads();

    // Phase 2: bin max ch1
    if (t < 196) {
        float m = -FLT_MAX;
        for (int r = sr + s; r < er; r += 4) {
            const float* rowp = lds + r * LROW;
            for (int cc = sc; cc < ec; ++cc)
                m = fmaxf(m, rowp[cc]);
        }
        m = fmaxf(m, __shfl_xor(m, 1, 64));
        m = fmaxf(m, __shfl_xor(m, 2, 64));
        if (s == 0) pooled[49 + o] = m;
    }
    __syncthreads();

    // Phase 3: FC (98 -> 4), 32 lanes per output, shfl_xor tree reduce
    if (t < 128) {
        const int oo = t >> 5;          // 0..3
        const int lane = t & 31;
        const float* wrow = fc_w + oo * 98;
        float acc = 0.f;
        #pragma unroll
        for (int k = lane; k < 98; k += 32)
            acc = fmaf(pooled[k], wrow[k], acc);
        #pragma unroll
        for (int m = 16; m; m >>= 1)
            acc += __shfl_xor(acc, m, 64);   // mask<32 stays within 32-lane group
        if (lane == 0) delta[oo] = fmaxf(acc + fc_b[oo], 0.f);
    }
    __syncthreads();

    if (t < 6) {
        float v = boxes[n * 6 + t];
        if (t >= 2) v += delta[t - 2];
        out[n * 6 + t] = v;
    }
}

extern "C" void kernel_launch(void* const* d_in, const int* in_sizes, int n_in,
                              void* d_out, int out_size, void* d_ws, size_t ws_size,
                              hipStream_t stream) {
    const float* feature = (const float*)d_in[0];  // [1,2,2048,2048] fp32
    const float* boxes   = (const float*)d_in[1];  // [N,6] fp32
    const int*   coords  = (const int*)d_in[2];    // [N,4] int32
    const float* fc_w    = (const float*)d_in[3];  // [4,98] fp32
    const float* fc_b    = (const float*)d_in[4];  // [4] fp32
    float* out = (float*)d_out;                    // [N,6] fp32

    const int N = in_sizes[2] / 4;
    roi_pool_fc_kernel<<<N, 256, 0, stream>>>(feature, boxes, coords, fc_w, fc_b, out, N);
}

// Round 4
// 85.087 us; speedup vs baseline: 1.2667x; 1.0523x over previous
//
#include <hip/hip_runtime.h>
#include <float.h>

#define POOL 7
#define FW 2048
#define FH 2048
#define CROP 96
#define LROW 100   // floats per LDS row (25 float4, 16B-aligned row base)

// One block per box.
//  Stage ch0 window (rows < h, float4 col-groups < wvec) -> regs -> LDS.
//  Bin-max ch0 via predicated float4 LDS reads (4 threads/output, shfl combine)
//  while ch1 global loads are in flight; repeat for ch1; tiny FC + ReLU + add.
__global__ __launch_bounds__(256, 4) void roi_pool_fc_kernel(
    const float* __restrict__ feature,   // [2, 2048, 2048]
    const float* __restrict__ boxes,     // [N, 6]
    const int*   __restrict__ coords,    // [N, 4] (y1, x1, y2, x2)
    const float* __restrict__ fc_w,      // [4, 98]
    const float* __restrict__ fc_b,      // [4]
    float* __restrict__ out,             // [N, 6]
    int N)
{
    const int n = blockIdx.x;
    const int t = threadIdx.x;

    __shared__ float lds[CROP * LROW];   // 38,400 B -> 4 blocks/CU
    __shared__ float pooled[98];         // channel-major: c*49 + i*7 + j
    __shared__ float delta[4];

    const int y1 = coords[n * 4 + 0];
    const int x1 = coords[n * 4 + 1];
    const int h  = coords[n * 4 + 2] - y1;   // 7 <= h <= 96
    const int w  = coords[n * 4 + 3] - x1;   // 7 <= w <= 96

    const int x1a  = x1 & ~3;              // 16B-aligned window start
    const int off  = x1 - x1a;             // 0..3
    const int wvec = (w + off + 3) >> 2;   // float4 groups actually needed per row

    // Compute-phase mapping: t -> (output o, row-split slot s)
    const int o = t >> 2;           // 0..48 for t < 196
    const int s = t & 3;
    const int i = o / 7;
    const int j = o % 7;
    int sr = 0, er = 0, sc = 0, ec = 0, sc4 = 0, ec4 = 0;
    if (t < 196) {
        sr  = (i * h) / POOL;
        er  = ((i + 1) * h + POOL - 1) / POOL;          // er <= h
        sc  = (j * w) / POOL + off;
        ec  = ((j + 1) * w + POOL - 1) / POOL + off;    // ec <= w+off <= 4*wvec
        sc4 = sc >> 2;
        ec4 = (ec + 3) >> 2;
    }

    // Staging geometry: up to 96 rows x 25 float4 = 2400 vecs; 10 chunks of 256.
    const float* b0 = feature + (size_t)y1 * FW + x1a;   // ch0
    const float* b1 = b0 + (size_t)FH * FW;              // ch1

    float4 regs[10];
    int vrow[10], vc4[10];
    bool vok[10];
    #pragma unroll
    for (int k = 0; k < 10; ++k) {
        const int v = t + k * 256;
        const int r = v / 25;
        vrow[k] = r;
        vc4[k]  = v - r * 25;
        vok[k]  = (v < 2400) && (r < h) && (vc4[k] < wvec);
        regs[k] = vok[k] ? ((const float4*)(b0 + (size_t)r * FW))[vc4[k]]
                         : make_float4(0.f, 0.f, 0.f, 0.f);
    }
    #pragma unroll
    for (int k = 0; k < 10; ++k)
        if (vok[k]) ((float4*)&lds[vrow[k] * LROW])[vc4[k]] = regs[k];
    __syncthreads();

    // Prefetch ch1 into regs while ch0 bin-max runs
    #pragma unroll
    for (int k = 0; k < 10; ++k)
        regs[k] = vok[k] ? ((const float4*)(b1 + (size_t)vrow[k] * FW))[vc4[k]]
                         : make_float4(0.f, 0.f, 0.f, 0.f);

    // Phase 1: bin max ch0 — predicated float4 LDS reads
    if (t < 196) {
        float m = -FLT_MAX;
        for (int r = sr + s; r < er; r += 4) {
            const float4* rowp = (const float4*)(lds + r * LROW);
            for (int c4 = sc4; c4 < ec4; ++c4) {
                const float4 v = rowp[c4];
                const int b = c4 * 4;
                m = fmaxf(m, (b + 0 >= sc && b + 0 < ec) ? v.x : -FLT_MAX);
                m = fmaxf(m, (b + 1 >= sc && b + 1 < ec) ? v.y : -FLT_MAX);
                m = fmaxf(m, (b + 2 >= sc && b + 2 < ec) ? v.z : -FLT_MAX);
                m = fmaxf(m, (b + 3 >= sc && b + 3 < ec) ? v.w : -FLT_MAX);
            }
        }
        m = fmaxf(m, __shfl_xor(m, 1, 64));
        m = fmaxf(m, __shfl_xor(m, 2, 64));
        if (s == 0) pooled[o] = m;
    }
    __syncthreads();   // all ch0 LDS reads done before overwrite

    #pragma unroll
    for (int k = 0; k < 10; ++k)
        if (vok[k]) ((float4*)&lds[vrow[k] * LROW])[vc4[k]] = regs[k];
    __syncthreads();

    // Phase 2: bin max ch1
    if (t < 196) {
        float m = -FLT_MAX;
        for (int r = sr + s; r < er; r += 4) {
            const float4* rowp = (const float4*)(lds + r * LROW);
            for (int c4 = sc4; c4 < ec4; ++c4) {
                const float4 v = rowp[c4];
                const int b = c4 * 4;
                m = fmaxf(m, (b + 0 >= sc && b + 0 < ec) ? v.x : -FLT_MAX);
                m = fmaxf(m, (b + 1 >= sc && b + 1 < ec) ? v.y : -FLT_MAX);
                m = fmaxf(m, (b + 2 >= sc && b + 2 < ec) ? v.z : -FLT_MAX);
                m = fmaxf(m, (b + 3 >= sc && b + 3 < ec) ? v.w : -FLT_MAX);
            }
        }
        m = fmaxf(m, __shfl_xor(m, 1, 64));
        m = fmaxf(m, __shfl_xor(m, 2, 64));
        if (s == 0) pooled[49 + o] = m;
    }
    __syncthreads();

    // Phase 3: FC (98 -> 4), 32 lanes per output, shfl_xor tree reduce
    if (t < 128) {
        const int oo   = t >> 5;        // 0..3
        const int lane = t & 31;
        const float* wrow = fc_w + oo * 98;
        float acc = 0.f;
        #pragma unroll
        for (int k = lane; k < 98; k += 32)
            acc = fmaf(pooled[k], wrow[k], acc);
        #pragma unroll
        for (int m = 16; m; m >>= 1)
            acc += __shfl_xor(acc, m, 64);   // mask<32 stays within 32-lane group
        if (lane == 0) delta[oo] = fmaxf(acc + fc_b[oo], 0.f);
    }
    __syncthreads();

    if (t < 6) {
        float v = boxes[n * 6 + t];
        if (t >= 2) v += delta[t - 2];
        out[n * 6 + t] = v;
    }
}

extern "C" void kernel_launch(void* const* d_in, const int* in_sizes, int n_in,
                              void* d_out, int out_size, void* d_ws, size_t ws_size,
                              hipStream_t stream) {
    const float* feature = (const float*)d_in[0];  // [1,2,2048,2048] fp32
    const float* boxes   = (const float*)d_in[1];  // [N,6] fp32
    const int*   coords  = (const int*)d_in[2];    // [N,4] int32
    const float* fc_w    = (const float*)d_in[3];  // [4,98] fp32
    const float* fc_b    = (const float*)d_in[4];  // [4] fp32
    float* out = (float*)d_out;                    // [N,6] fp32

    const int N = in_sizes[2] / 4;
    roi_pool_fc_kernel<<<N, 256, 0, stream>>>(feature, boxes, coords, fc_w, fc_b, out, N);
}